// Round 15
// baseline (443.255 us; speedup 1.0000x reference)
//
#include <hip/hip_runtime.h>
#include <hip/hip_bf16.h>

#define C 128
#define RBFD 20
#define NATOMS 50000
#define SLAB 128          // edges per gather slab; 800000 % 128 == 0
#define SS 32             // sub-slab size (edges per pipeline stage)
#define NSS (SLAB / SS)   // 4 sub-slabs per slab

// ---------------------------------------------------------------------------
// Kernel 1: setup — transpose W1, W2 into [in][out], zero histogram counters,
// zero the accumulator (boundary atomics + zero-edge atoms need zeros).
// ---------------------------------------------------------------------------
__global__ __launch_bounds__(256) void setup_kernel(
    const float* __restrict__ W1, const float* __restrict__ W2,
    float* __restrict__ W1T, float* __restrict__ W2T,
    int* __restrict__ count, float4* __restrict__ acc4,
    int n, int acc_quads)
{
    const int t = blockIdx.x * blockDim.x + threadIdx.x;
    const int stride = gridDim.x * blockDim.x;
    if (t < C * C) {
        int k = t / C;
        int c = t % C;
        W1T[t] = W1[c * C + k];
        W2T[t] = W2[c * C + k];
    }
    for (int i = t; i < n; i += stride) count[i] = 0;
    const float4 z = make_float4(0.f, 0.f, 0.f, 0.f);
    for (int i = t; i < acc_quads; i += stride) acc4[i] = z;
}

// ---------------------------------------------------------------------------
// Kernel 2: histogram of edge destinations.
// ---------------------------------------------------------------------------
__global__ __launch_bounds__(256) void histogram_kernel(
    const int* __restrict__ idx, int* __restrict__ count, int E)
{
    int e = blockIdx.x * blockDim.x + threadIdx.x;
    if (e < E) atomicAdd(&count[idx[e]], 1);
}

// ---------------------------------------------------------------------------
// Kernel 3: single-block exclusive scan over count[NATOMS] -> base, cursor.
// Each thread owns a contiguous 49-element range (compile-time bound -> full
// unroll, batched independent loads), then a 1024-wide LDS scan stitches the
// per-thread totals.  Replaces the previous 3-kernel scan cascade.
// ---------------------------------------------------------------------------
#define SCAN_T 1024
#define SCAN_CH ((NATOMS + SCAN_T - 1) / SCAN_T)   // 49

__global__ __launch_bounds__(SCAN_T) void scan_kernel(
    const int* __restrict__ count, int* __restrict__ base,
    int* __restrict__ cursor)
{
    __shared__ int sm[SCAN_T];
    const int t  = threadIdx.x;
    const int s0 = t * SCAN_CH;

    int v[SCAN_CH];
#pragma unroll
    for (int k = 0; k < SCAN_CH; ++k) {
        const int i = s0 + k;
        v[k] = (i < NATOMS) ? count[i] : 0;
    }
    int run = 0;
#pragma unroll
    for (int k = 0; k < SCAN_CH; ++k) { int tv = v[k]; v[k] = run; run += tv; }

    sm[t] = run;
    __syncthreads();
    for (int off = 1; off < SCAN_T; off <<= 1) {
        int tmp = (t >= off) ? sm[t - off] : 0;
        __syncthreads();
        sm[t] += tmp;
        __syncthreads();
    }
    const int offset = sm[t] - run;   // exclusive prefix of this thread's range

#pragma unroll
    for (int k = 0; k < SCAN_CH; ++k) {
        const int i = s0 + k;
        if (i < NATOMS) {
            const int b = v[k] + offset;
            base[i]   = b;
            cursor[i] = b;
        }
    }
    if (t == SCAN_T - 1) base[NATOMS] = sm[SCAN_T - 1];
}

// ---------------------------------------------------------------------------
// Kernel 4: fill perm (CSR order) + owner array.
// ---------------------------------------------------------------------------
__global__ __launch_bounds__(256) void fill_perm_kernel(
    const int* __restrict__ idx, int* __restrict__ cursor,
    int* __restrict__ perm, int* __restrict__ own, int E)
{
    int e = blockIdx.x * blockDim.x + threadIdx.x;
    if (e < E) {
        int a = idx[e];
        int pos = atomicAdd(&cursor[a], 1);
        perm[pos] = e;
        own[pos] = a;
    }
}

// ---------------------------------------------------------------------------
// Gather kernel v12: r13's measured-best pipeline (cooperative rbf->LDS
// ping-pong, x double-buffered in registers, raw s_barrier without vmcnt
// drain, segmented flush) wrapped in a grid-stride slab loop:
//  * 2048 persistent blocks each process ~3 slabs; Wrbf row + bias loaded
//    ONCE per block (was per slab), dispatch churn 6250 -> 2048.
//  * Per-slab structure and barrier counts identical across both waves.
// NOTE on the plateau: 10 schedule variants converge at ~240-260us; the
// limiter is the per-CU outstanding-request (MSHR) cap x loaded latency on
// random 512B reads (~1.9-2.2 TB/s delivered), not the schedule.
// ---------------------------------------------------------------------------
__global__ __launch_bounds__(128, 2) void gather_kernel(
    const float* __restrict__ x,       // [E][C]
    const float* __restrict__ rbf,     // [E][RBFD]
    const float* __restrict__ env,     // [E]
    const int*   __restrict__ perm,    // [E]
    const int*   __restrict__ own,     // [E]
    const float* __restrict__ Wrbf,    // [C][RBFD]
    const float* __restrict__ brbf,    // [C]
    float* __restrict__ acc,           // [N][C] (pre-zeroed)
    int nslabs)
{
    __shared__ int   e_s[SLAB];
    __shared__ float env_s[SLAB];
    __shared__ int   own_s[SLAB];
    __shared__ float rbf_s[2][SS][RBFD];

    const int tid = threadIdx.x;      // 0..127, = channel

    float w[RBFD];
#pragma unroll
    for (int r = 0; r < RBFD; ++r) w[r] = Wrbf[tid * RBFD + r];
    const float bias = brbf[tid];

#define FLUSH()                                                                \
    do {                                                                       \
        if (cur_own == first_own)                                              \
            unsafeAtomicAdd(&acc[(size_t)cur_own * C + tid], sum);             \
        else acc[(size_t)cur_own * C + tid] = sum;                             \
    } while (0)

    for (int slab = blockIdx.x; slab < nslabs; slab += gridDim.x) {
        const int p0 = slab * SLAB;

        __syncthreads();   // previous slab's consumers done before restage
        {
            const int e = perm[p0 + tid];
            e_s[tid]   = e;
            env_s[tid] = env[e];
            own_s[tid] = own[p0 + tid];
        }
        __syncthreads();

        const int first_own = own_s[0];
        int   cur_own = first_own;
        float sum = 0.0f;

        float xr[2][SS];
        float st[5];

        // ---- prologue: stage sub-slab 0 ----
#pragma unroll
        for (int p = 0; p < 5; ++p) {
            const int g = p * 128 + tid;
            st[p] = rbf[(size_t)e_s[g / RBFD] * RBFD + (g % RBFD)];
        }
#pragma unroll
        for (int i = 0; i < SS; ++i)
            xr[0][i] = x[(size_t)e_s[i] * C + tid];
        __builtin_amdgcn_sched_barrier(0);
#pragma unroll
        for (int p = 0; p < 5; ++p) {
            const int g = p * 128 + tid;
            rbf_s[0][g / RBFD][g % RBFD] = st[p];
        }
        __syncthreads();

#pragma unroll
        for (int ss = 0; ss < NSS; ++ss) {
            const int sbase = ss * SS;
            const int cur   = ss & 1;

            // ---- issue next sub-slab's loads ----
            if (ss + 1 < NSS) {
#pragma unroll
                for (int p = 0; p < 5; ++p) {
                    const int g = p * 128 + tid;
                    st[p] = rbf[(size_t)e_s[sbase + SS + g / RBFD] * RBFD + (g % RBFD)];
                }
#pragma unroll
                for (int i = 0; i < SS; ++i)
                    xr[cur ^ 1][i] = x[(size_t)e_s[sbase + SS + i] * C + tid];
            }
            __builtin_amdgcn_sched_barrier(0);

            // ---- compute current sub-slab ----
#pragma unroll
            for (int j = 0; j < SS; ++j) {
                const float4* q = reinterpret_cast<const float4*>(&rbf_s[cur][j][0]);
                const float4 a = q[0], b = q[1], c = q[2], d = q[3], e4 = q[4];
                float f = bias;
                f = fmaf(a.x,  w[0],  f); f = fmaf(a.y,  w[1],  f);
                f = fmaf(a.z,  w[2],  f); f = fmaf(a.w,  w[3],  f);
                f = fmaf(b.x,  w[4],  f); f = fmaf(b.y,  w[5],  f);
                f = fmaf(b.z,  w[6],  f); f = fmaf(b.w,  w[7],  f);
                f = fmaf(c.x,  w[8],  f); f = fmaf(c.y,  w[9],  f);
                f = fmaf(c.z,  w[10], f); f = fmaf(c.w,  w[11], f);
                f = fmaf(d.x,  w[12], f); f = fmaf(d.y,  w[13], f);
                f = fmaf(d.z,  w[14], f); f = fmaf(d.w,  w[15], f);
                f = fmaf(e4.x, w[16], f); f = fmaf(e4.y, w[17], f);
                f = fmaf(e4.z, w[18], f); f = fmaf(e4.w, w[19], f);

                const float v = f * env_s[sbase + j] * xr[cur][j];
                const int   o = own_s[sbase + j];
                if (o != cur_own) { FLUSH(); sum = 0.0f; cur_own = o; }
                sum += v;
            }
            __builtin_amdgcn_sched_barrier(0);

            // ---- ds_write staged rbf; barrier WITHOUT vmcnt drain ----
            if (ss + 1 < NSS) {
#pragma unroll
                for (int p = 0; p < 5; ++p) {
                    const int g = p * 128 + tid;
                    rbf_s[cur ^ 1][g / RBFD][g % RBFD] = st[p];
                }
                asm volatile("s_waitcnt lgkmcnt(0)" ::: "memory");
                __builtin_amdgcn_sched_barrier(0);
                __builtin_amdgcn_s_barrier();
            }
        }
        // final flush: cur_own may span into next slab -> atomic
        unsafeAtomicAdd(&acc[(size_t)cur_own * C + tid], sum);
    }
#undef FLUSH
}

// ---------------------------------------------------------------------------
// Fused MLP head (unchanged).
// ---------------------------------------------------------------------------
__device__ __forceinline__ float silu_f(float v) {
    return v * (1.0f / (1.0f + __expf(-v)));
}

__global__ __launch_bounds__(256) void mlp_head_kernel(
    const float* __restrict__ acc,   // [N][C]
    const float* __restrict__ W1T,   // [C][C]  (k-major)
    const float* __restrict__ b1,    // [C]
    const float* __restrict__ W2T,   // [C][C]
    const float* __restrict__ b2,    // [C]
    const float* __restrict__ W3,    // [1][C]
    const float* __restrict__ b3,    // [1]
    float* __restrict__ out,         // [N]
    int natoms)
{
    __shared__ float As[C][C + 1];

    const int tid = threadIdx.x;
    const int a0  = blockIdx.x * C;
    const int tc  = tid & 15;
    const int ta  = tid >> 4;
    const int abase = ta * 8;
    const int cbase = tc * 8;

    {
        const int sub = tid >> 7;
        const int k   = tid & 127;
        for (int pair = 0; pair < 64; ++pair) {
            const int al = pair * 2 + sub;
            const int a  = a0 + al;
            float v = (a < natoms) ? acc[(size_t)a * C + k] : 0.0f;
            As[k][al] = v;
        }
    }
    __syncthreads();

    float r[8][8];

    // layer 1
#pragma unroll
    for (int i = 0; i < 8; ++i)
#pragma unroll
        for (int j = 0; j < 8; ++j) r[i][j] = 0.0f;

#pragma unroll 2
    for (int k = 0; k < C; ++k) {
        float4 bq0 = *reinterpret_cast<const float4*>(W1T + k * C + cbase);
        float4 bq1 = *reinterpret_cast<const float4*>(W1T + k * C + cbase + 4);
        float bv[8] = {bq0.x, bq0.y, bq0.z, bq0.w, bq1.x, bq1.y, bq1.z, bq1.w};
        float av[8];
#pragma unroll
        for (int i = 0; i < 8; ++i) av[i] = As[k][abase + i];
#pragma unroll
        for (int i = 0; i < 8; ++i)
#pragma unroll
            for (int j = 0; j < 8; ++j) r[i][j] = fmaf(av[i], bv[j], r[i][j]);
    }

    __syncthreads();
    {
        float bb[8];
#pragma unroll
        for (int j = 0; j < 8; ++j) bb[j] = b1[cbase + j];
#pragma unroll
        for (int i = 0; i < 8; ++i)
#pragma unroll
            for (int j = 0; j < 8; ++j)
                As[cbase + j][abase + i] = silu_f(r[i][j] + bb[j]);
    }
    __syncthreads();

    // layer 2
#pragma unroll
    for (int i = 0; i < 8; ++i)
#pragma unroll
        for (int j = 0; j < 8; ++j) r[i][j] = 0.0f;

#pragma unroll 2
    for (int k = 0; k < C; ++k) {
        float4 bq0 = *reinterpret_cast<const float4*>(W2T + k * C + cbase);
        float4 bq1 = *reinterpret_cast<const float4*>(W2T + k * C + cbase + 4);
        float bv[8] = {bq0.x, bq0.y, bq0.z, bq0.w, bq1.x, bq1.y, bq1.z, bq1.w};
        float av[8];
#pragma unroll
        for (int i = 0; i < 8; ++i) av[i] = As[k][abase + i];
#pragma unroll
        for (int i = 0; i < 8; ++i)
#pragma unroll
            for (int j = 0; j < 8; ++j) r[i][j] = fmaf(av[i], bv[j], r[i][j]);
    }

    __syncthreads();

    // final: silu(.. + b2) . W3
    {
        float bb[8], w3v[8];
#pragma unroll
        for (int j = 0; j < 8; ++j) bb[j] = b2[cbase + j];
        float4 wq0 = *reinterpret_cast<const float4*>(W3 + cbase);
        float4 wq1 = *reinterpret_cast<const float4*>(W3 + cbase + 4);
        w3v[0]=wq0.x; w3v[1]=wq0.y; w3v[2]=wq0.z; w3v[3]=wq0.w;
        w3v[4]=wq1.x; w3v[5]=wq1.y; w3v[6]=wq1.z; w3v[7]=wq1.w;

#pragma unroll
        for (int i = 0; i < 8; ++i) {
            float p = 0.0f;
#pragma unroll
            for (int j = 0; j < 8; ++j)
                p = fmaf(silu_f(r[i][j] + bb[j]), w3v[j], p);
            As[abase + i][tc] = p;
        }
    }
    __syncthreads();

    if (tid < C) {
        const int a = a0 + tid;
        if (a < natoms) {
            float s = 0.0f;
#pragma unroll
            for (int t = 0; t < 16; ++t) s += As[tid][t];
            out[a] = s + b3[0];
        }
    }
}

// ---------------------------------------------------------------------------
extern "C" void kernel_launch(void* const* d_in, const int* in_sizes, int n_in,
                              void* d_out, int out_size, void* d_ws, size_t ws_size,
                              hipStream_t stream) {
    const float* x      = (const float*)d_in[0];
    const float* rbf    = (const float*)d_in[1];
    const float* env    = (const float*)d_in[2];
    const int*   idx    = (const int*)  d_in[3];
    const float* Wrbf   = (const float*)d_in[5];
    const float* brbf   = (const float*)d_in[6];
    const float* W1     = (const float*)d_in[7];
    const float* b1     = (const float*)d_in[8];
    const float* W2     = (const float*)d_in[9];
    const float* b2     = (const float*)d_in[10];
    const float* W3     = (const float*)d_in[11];
    const float* b3     = (const float*)d_in[12];
    float*       out    = (float*)d_out;

    const int E = in_sizes[0] / C;        // 800000
    const int N = NATOMS;                 // 50000

    // workspace layout
    float* acc     = (float*)d_ws;                    // N*C
    float* W1T     = acc + (size_t)N * C;             // C*C
    float* W2T     = W1T + C * C;                     // C*C
    int*   count   = (int*)(W2T + C * C);             // N
    int*   base    = count + N;                       // N+1
    int*   cursor  = base + (N + 1);                  // N
    int*   perm    = cursor + N;                      // E
    int*   own     = perm + E;                        // E

    // setup: transpose weights + zero counters + zero acc
    setup_kernel<<<2048, 256, 0, stream>>>(W1, W2, W1T, W2T, count,
                                           (float4*)acc, N, (N * C) / 4);

    histogram_kernel<<<(E + 255) / 256, 256, 0, stream>>>(idx, count, E);
    scan_kernel<<<1, SCAN_T, 0, stream>>>(count, base, cursor);
    fill_perm_kernel<<<(E + 255) / 256, 256, 0, stream>>>(idx, cursor, perm, own, E);

    // gather: 2048 persistent blocks, grid-stride over E/SLAB slabs
    gather_kernel<<<2048, 128, 0, stream>>>(x, rbf, env, perm, own,
                                            Wrbf, brbf, acc, E / SLAB);

    const int tiles = (N + C - 1) / C;
    mlp_head_kernel<<<tiles, 256, 0, stream>>>(acc, W1T, b1, W2T, b2, W3, b3, out, N);
}

// Round 16
// 387.530 us; speedup vs baseline: 1.1438x; 1.1438x over previous
//
#include <hip/hip_runtime.h>
#include <hip/hip_bf16.h>

#define C 128
#define RBFD 20
#define NATOMS 50000
#define SLAB 128          // edges per gather block; 800000 % 128 == 0
#define SS 32             // sub-slab size (edges per pipeline stage)
#define NSS (SLAB / SS)   // 4 sub-slabs per slab
#define MA 64             // atoms per MLP block

// ---------------------------------------------------------------------------
// Kernel 1: setup — transpose W1, W2 into [in][out], zero histogram counters,
// zero the accumulator (boundary atomics + zero-edge atoms need zeros).
// ---------------------------------------------------------------------------
__global__ __launch_bounds__(256) void setup_kernel(
    const float* __restrict__ W1, const float* __restrict__ W2,
    float* __restrict__ W1T, float* __restrict__ W2T,
    int* __restrict__ count, float4* __restrict__ acc4,
    int n, int acc_quads)
{
    const int t = blockIdx.x * blockDim.x + threadIdx.x;
    const int stride = gridDim.x * blockDim.x;
    if (t < C * C) {
        int k = t / C;
        int c = t % C;
        W1T[t] = W1[c * C + k];
        W2T[t] = W2[c * C + k];
    }
    for (int i = t; i < n; i += stride) count[i] = 0;
    const float4 z = make_float4(0.f, 0.f, 0.f, 0.f);
    for (int i = t; i < acc_quads; i += stride) acc4[i] = z;
}

// ---------------------------------------------------------------------------
// Kernel 2: histogram of edge destinations.
// ---------------------------------------------------------------------------
__global__ __launch_bounds__(256) void histogram_kernel(
    const int* __restrict__ idx, int* __restrict__ count, int E)
{
    int e = blockIdx.x * blockDim.x + threadIdx.x;
    if (e < E) atomicAdd(&count[idx[e]], 1);
}

// ---------------------------------------------------------------------------
// Kernel 3: single-block exclusive scan over count[NATOMS] -> base, cursor.
// ---------------------------------------------------------------------------
#define SCAN_T 1024
#define SCAN_CH ((NATOMS + SCAN_T - 1) / SCAN_T)   // 49

__global__ __launch_bounds__(SCAN_T) void scan_kernel(
    const int* __restrict__ count, int* __restrict__ base,
    int* __restrict__ cursor)
{
    __shared__ int sm[SCAN_T];
    const int t  = threadIdx.x;
    const int s0 = t * SCAN_CH;

    int v[SCAN_CH];
#pragma unroll
    for (int k = 0; k < SCAN_CH; ++k) {
        const int i = s0 + k;
        v[k] = (i < NATOMS) ? count[i] : 0;
    }
    int run = 0;
#pragma unroll
    for (int k = 0; k < SCAN_CH; ++k) { int tv = v[k]; v[k] = run; run += tv; }

    sm[t] = run;
    __syncthreads();
    for (int off = 1; off < SCAN_T; off <<= 1) {
        int tmp = (t >= off) ? sm[t - off] : 0;
        __syncthreads();
        sm[t] += tmp;
        __syncthreads();
    }
    const int offset = sm[t] - run;

#pragma unroll
    for (int k = 0; k < SCAN_CH; ++k) {
        const int i = s0 + k;
        if (i < NATOMS) {
            const int b = v[k] + offset;
            base[i]   = b;
            cursor[i] = b;
        }
    }
    if (t == SCAN_T - 1) base[NATOMS] = sm[SCAN_T - 1];
}

// ---------------------------------------------------------------------------
// Kernel 4: fill perm (CSR order) + owner array.
// ---------------------------------------------------------------------------
__global__ __launch_bounds__(256) void fill_perm_kernel(
    const int* __restrict__ idx, int* __restrict__ cursor,
    int* __restrict__ perm, int* __restrict__ own, int E)
{
    int e = blockIdx.x * blockDim.x + threadIdx.x;
    if (e < E) {
        int a = idx[e];
        int pos = atomicAdd(&cursor[a], 1);
        perm[pos] = e;
        own[pos] = a;
    }
}

// ---------------------------------------------------------------------------
// Gather kernel: EXACT round-10 form (best measured: 243 us, total 329.7).
// One 128-thread block (thread = channel) per 128-edge slab; cooperative rbf
// staging to LDS ping-pong; x double-buffered in registers; segmented
// flush-on-owner-change with atomics only at slab boundaries.
// Plateau note: 11 schedule variants (incl. asm+counted-vmcnt) converge at
// ~242-260us ≈ 2.0 TB/s delivered on random 512B/128B granules — a memory
// concurrency wall, not a scheduling artifact.
// ---------------------------------------------------------------------------
__global__ __launch_bounds__(128, 2) void gather_kernel(
    const float* __restrict__ x,       // [E][C]
    const float* __restrict__ rbf,     // [E][RBFD]
    const float* __restrict__ env,     // [E]
    const int*   __restrict__ perm,    // [E]
    const int*   __restrict__ own,     // [E]
    const float* __restrict__ Wrbf,    // [C][RBFD]
    const float* __restrict__ brbf,    // [C]
    float* __restrict__ acc)           // [N][C] (pre-zeroed)
{
    __shared__ int   e_s[SLAB];
    __shared__ float env_s[SLAB];
    __shared__ int   own_s[SLAB];
    __shared__ float rbf_s[2][SS][RBFD];

    const int tid = threadIdx.x;      // 0..127, = channel
    const int p0  = blockIdx.x * SLAB;

    {
        const int e = perm[p0 + tid];
        e_s[tid]   = e;
        env_s[tid] = env[e];
        own_s[tid] = own[p0 + tid];
    }

    float w[RBFD];
#pragma unroll
    for (int r = 0; r < RBFD; ++r) w[r] = Wrbf[tid * RBFD + r];
    const float bias = brbf[tid];

    __syncthreads();

    const int first_own = own_s[0];
    int   cur_own = first_own;
    float sum = 0.0f;

#define FLUSH()                                                                \
    do {                                                                       \
        if (cur_own == first_own)                                              \
            unsafeAtomicAdd(&acc[(size_t)cur_own * C + tid], sum);             \
        else acc[(size_t)cur_own * C + tid] = sum;                             \
    } while (0)

    float xr[2][SS];   // x double-buffer (fully unrolled -> registers)
    float st[5];       // rbf staging registers

    // ---- prologue: stage sub-slab 0 ----
#pragma unroll
    for (int p = 0; p < 5; ++p) {
        const int g = p * 128 + tid;            // 0..639
        st[p] = rbf[(size_t)e_s[g / RBFD] * RBFD + (g % RBFD)];
    }
#pragma unroll
    for (int i = 0; i < SS; ++i)
        xr[0][i] = x[(size_t)e_s[i] * C + tid];
    __builtin_amdgcn_sched_barrier(0);
#pragma unroll
    for (int p = 0; p < 5; ++p) {
        const int g = p * 128 + tid;
        rbf_s[0][g / RBFD][g % RBFD] = st[p];
    }
    __syncthreads();

#pragma unroll
    for (int ss = 0; ss < NSS; ++ss) {
        const int sbase = ss * SS;
        const int cur   = ss & 1;

        // ---- issue next sub-slab's loads (rbf -> regs, x -> regs) ----
        if (ss + 1 < NSS) {
#pragma unroll
            for (int p = 0; p < 5; ++p) {
                const int g = p * 128 + tid;
                st[p] = rbf[(size_t)e_s[sbase + SS + g / RBFD] * RBFD + (g % RBFD)];
            }
#pragma unroll
            for (int i = 0; i < SS; ++i)
                xr[cur ^ 1][i] = x[(size_t)e_s[sbase + SS + i] * C + tid];
        }
        __builtin_amdgcn_sched_barrier(0);

        // ---- compute current sub-slab (LDS broadcasts + registers only) ----
#pragma unroll
        for (int j = 0; j < SS; ++j) {
            const float4* q = reinterpret_cast<const float4*>(&rbf_s[cur][j][0]);
            const float4 a = q[0], b = q[1], c = q[2], d = q[3], e4 = q[4];
            float f = bias;
            f = fmaf(a.x,  w[0],  f); f = fmaf(a.y,  w[1],  f);
            f = fmaf(a.z,  w[2],  f); f = fmaf(a.w,  w[3],  f);
            f = fmaf(b.x,  w[4],  f); f = fmaf(b.y,  w[5],  f);
            f = fmaf(b.z,  w[6],  f); f = fmaf(b.w,  w[7],  f);
            f = fmaf(c.x,  w[8],  f); f = fmaf(c.y,  w[9],  f);
            f = fmaf(c.z,  w[10], f); f = fmaf(c.w,  w[11], f);
            f = fmaf(d.x,  w[12], f); f = fmaf(d.y,  w[13], f);
            f = fmaf(d.z,  w[14], f); f = fmaf(d.w,  w[15], f);
            f = fmaf(e4.x, w[16], f); f = fmaf(e4.y, w[17], f);
            f = fmaf(e4.z, w[18], f); f = fmaf(e4.w, w[19], f);

            const float v = f * env_s[sbase + j] * xr[cur][j];
            const int   o = own_s[sbase + j];
            if (o != cur_own) { FLUSH(); sum = 0.0f; cur_own = o; }
            sum += v;
        }

        // ---- write staged rbf to the other LDS buffer ----
        if (ss + 1 < NSS) {
#pragma unroll
            for (int p = 0; p < 5; ++p) {
                const int g = p * 128 + tid;
                rbf_s[cur ^ 1][g / RBFD][g % RBFD] = st[p];
            }
        }
        __syncthreads();
    }
    // final flush: cur_own may span into next slab -> atomic
    unsafeAtomicAdd(&acc[(size_t)cur_own * C + tid], sum);
#undef FLUSH
}

// ---------------------------------------------------------------------------
// Fused MLP head: 64 atoms per block (782 blocks -> ~3 blocks/CU, was 1.5).
// 256 threads as 16x16 tiles of 4 atoms x 8 outs.  As = [k][atom] 128x65
// (33 KB; stride 65 -> conflict-free).
// ---------------------------------------------------------------------------
__device__ __forceinline__ float silu_f(float v) {
    return v * (1.0f / (1.0f + __expf(-v)));
}

__global__ __launch_bounds__(256) void mlp_head_kernel(
    const float* __restrict__ acc,   // [N][C]
    const float* __restrict__ W1T,   // [C][C]  (k-major)
    const float* __restrict__ b1,    // [C]
    const float* __restrict__ W2T,   // [C][C]
    const float* __restrict__ b2,    // [C]
    const float* __restrict__ W3,    // [1][C]
    const float* __restrict__ b3,    // [1]
    float* __restrict__ out,         // [N]
    int natoms)
{
    __shared__ float As[C][MA + 1];

    const int tid = threadIdx.x;
    const int a0  = blockIdx.x * MA;
    const int tc  = tid & 15;        // out-col tile (8 outs)
    const int ta  = tid >> 4;        // atom tile (4 atoms)
    const int abase = ta * 4;
    const int cbase = tc * 8;

    // ---- load h tile: 64 atoms x 128 k, coalesced (k contiguous) ----
#pragma unroll
    for (int pass = 0; pass < 32; ++pass) {
        const int idxl = pass * 256 + tid;    // 0..8191
        const int al = idxl >> 7;             // 0..63
        const int k  = idxl & 127;
        const int a  = a0 + al;
        As[k][al] = (a < natoms) ? acc[(size_t)a * C + k] : 0.0f;
    }
    __syncthreads();

    float r[4][8];

    // ---------------- layer 1 ----------------
#pragma unroll
    for (int i = 0; i < 4; ++i)
#pragma unroll
        for (int j = 0; j < 8; ++j) r[i][j] = 0.0f;

#pragma unroll 2
    for (int k = 0; k < C; ++k) {
        float4 bq0 = *reinterpret_cast<const float4*>(W1T + k * C + cbase);
        float4 bq1 = *reinterpret_cast<const float4*>(W1T + k * C + cbase + 4);
        float bv[8] = {bq0.x, bq0.y, bq0.z, bq0.w, bq1.x, bq1.y, bq1.z, bq1.w};
        float av[4];
#pragma unroll
        for (int i = 0; i < 4; ++i) av[i] = As[k][abase + i];
#pragma unroll
        for (int i = 0; i < 4; ++i)
#pragma unroll
            for (int j = 0; j < 8; ++j) r[i][j] = fmaf(av[i], bv[j], r[i][j]);
    }

    __syncthreads();
    {
        float bb[8];
#pragma unroll
        for (int j = 0; j < 8; ++j) bb[j] = b1[cbase + j];
#pragma unroll
        for (int i = 0; i < 4; ++i)
#pragma unroll
            for (int j = 0; j < 8; ++j)
                As[cbase + j][abase + i] = silu_f(r[i][j] + bb[j]);
    }
    __syncthreads();

    // ---------------- layer 2 ----------------
#pragma unroll
    for (int i = 0; i < 4; ++i)
#pragma unroll
        for (int j = 0; j < 8; ++j) r[i][j] = 0.0f;

#pragma unroll 2
    for (int k = 0; k < C; ++k) {
        float4 bq0 = *reinterpret_cast<const float4*>(W2T + k * C + cbase);
        float4 bq1 = *reinterpret_cast<const float4*>(W2T + k * C + cbase + 4);
        float bv[8] = {bq0.x, bq0.y, bq0.z, bq0.w, bq1.x, bq1.y, bq1.z, bq1.w};
        float av[4];
#pragma unroll
        for (int i = 0; i < 4; ++i) av[i] = As[k][abase + i];
#pragma unroll
        for (int i = 0; i < 4; ++i)
#pragma unroll
            for (int j = 0; j < 8; ++j) r[i][j] = fmaf(av[i], bv[j], r[i][j]);
    }

    __syncthreads();

    // ---------------- final: silu(.. + b2) . W3 ----------------
    {
        float bb[8], w3v[8];
#pragma unroll
        for (int j = 0; j < 8; ++j) bb[j] = b2[cbase + j];
        float4 wq0 = *reinterpret_cast<const float4*>(W3 + cbase);
        float4 wq1 = *reinterpret_cast<const float4*>(W3 + cbase + 4);
        w3v[0]=wq0.x; w3v[1]=wq0.y; w3v[2]=wq0.z; w3v[3]=wq0.w;
        w3v[4]=wq1.x; w3v[5]=wq1.y; w3v[6]=wq1.z; w3v[7]=wq1.w;

#pragma unroll
        for (int i = 0; i < 4; ++i) {
            float p = 0.0f;
#pragma unroll
            for (int j = 0; j < 8; ++j)
                p = fmaf(silu_f(r[i][j] + bb[j]), w3v[j], p);
            As[abase + i][tc] = p;   // partial per (atom, col-tile)
        }
    }
    __syncthreads();

    if (tid < MA) {
        const int a = a0 + tid;
        if (a < natoms) {
            float s = 0.0f;
#pragma unroll
            for (int t = 0; t < 16; ++t) s += As[tid][t];
            out[a] = s + b3[0];
        }
    }
}

// ---------------------------------------------------------------------------
extern "C" void kernel_launch(void* const* d_in, const int* in_sizes, int n_in,
                              void* d_out, int out_size, void* d_ws, size_t ws_size,
                              hipStream_t stream) {
    const float* x      = (const float*)d_in[0];
    const float* rbf    = (const float*)d_in[1];
    const float* env    = (const float*)d_in[2];
    const int*   idx    = (const int*)  d_in[3];
    const float* Wrbf   = (const float*)d_in[5];
    const float* brbf   = (const float*)d_in[6];
    const float* W1     = (const float*)d_in[7];
    const float* b1     = (const float*)d_in[8];
    const float* W2     = (const float*)d_in[9];
    const float* b2     = (const float*)d_in[10];
    const float* W3     = (const float*)d_in[11];
    const float* b3     = (const float*)d_in[12];
    float*       out    = (float*)d_out;

    const int E = in_sizes[0] / C;        // 800000
    const int N = NATOMS;                 // 50000

    // workspace layout
    float* acc     = (float*)d_ws;                    // N*C
    float* W1T     = acc + (size_t)N * C;             // C*C
    float* W2T     = W1T + C * C;                     // C*C
    int*   count   = (int*)(W2T + C * C);             // N
    int*   base    = count + N;                       // N+1
    int*   cursor  = base + (N + 1);                  // N
    int*   perm    = cursor + N;                      // E
    int*   own     = perm + E;                        // E

    // setup: transpose weights + zero counters + zero acc
    setup_kernel<<<2048, 256, 0, stream>>>(W1, W2, W1T, W2T, count,
                                           (float4*)acc, N, (N * C) / 4);

    histogram_kernel<<<(E + 255) / 256, 256, 0, stream>>>(idx, count, E);
    scan_kernel<<<1, SCAN_T, 0, stream>>>(count, base, cursor);
    fill_perm_kernel<<<(E + 255) / 256, 256, 0, stream>>>(idx, cursor, perm, own, E);

    // gather: one 128-thread block per 128-edge slab (round-10 exact)
    gather_kernel<<<E / SLAB, 128, 0, stream>>>(x, rbf, env, perm, own,
                                                Wrbf, brbf, acc);

    const int tiles = (N + MA - 1) / MA;
    mlp_head_kernel<<<tiles, 256, 0, stream>>>(acc, W1T, b1, W2T, b2, W3, b3, out, N);
}

// Round 17
// 330.811 us; speedup vs baseline: 1.3399x; 1.1715x over previous
//
#include <hip/hip_runtime.h>
#include <hip/hip_bf16.h>

#define C 128
#define RBFD 20
#define NATOMS 50000
#define SCAN_CHUNK 1024
#define SLAB 128          // edges per gather block; 800000 % 128 == 0
#define SS 32             // sub-slab size (edges per pipeline stage)
#define NSS (SLAB / SS)   // 4 sub-slabs per slab

// ---------------------------------------------------------------------------
// Kernel 1: setup — transpose W1, W2 into [in][out], zero histogram counters,
// zero the accumulator (needed: boundary atomics + atoms with zero edges).
// ---------------------------------------------------------------------------
__global__ __launch_bounds__(256) void setup_kernel(
    const float* __restrict__ W1, const float* __restrict__ W2,
    float* __restrict__ W1T, float* __restrict__ W2T,
    int* __restrict__ count, float4* __restrict__ acc4,
    int n, int acc_quads)
{
    const int t = blockIdx.x * blockDim.x + threadIdx.x;
    const int stride = gridDim.x * blockDim.x;
    if (t < C * C) {
        int k = t / C;   // in-channel
        int c = t % C;   // out-channel
        W1T[t] = W1[c * C + k];
        W2T[t] = W2[c * C + k];
    }
    for (int i = t; i < n; i += stride) count[i] = 0;
    const float4 z = make_float4(0.f, 0.f, 0.f, 0.f);
    for (int i = t; i < acc_quads; i += stride) acc4[i] = z;
}

// ---------------------------------------------------------------------------
// CSR construction: histogram -> hierarchical exclusive scan -> perm fill
// ---------------------------------------------------------------------------
__global__ __launch_bounds__(256) void histogram_kernel(
    const int* __restrict__ idx, int* __restrict__ count, int E)
{
    int e = blockIdx.x * blockDim.x + threadIdx.x;
    if (e < E) atomicAdd(&count[idx[e]], 1);
}

__global__ __launch_bounds__(256) void scan_partials_kernel(
    const int* __restrict__ count, int* __restrict__ partial, int n)
{
    __shared__ int sm[256];
    const int start = blockIdx.x * SCAN_CHUNK;
    int s = 0;
    for (int i = threadIdx.x; i < SCAN_CHUNK; i += 256) {
        int g = start + i;
        if (g < n) s += count[g];
    }
    sm[threadIdx.x] = s;
    __syncthreads();
    for (int off = 128; off > 0; off >>= 1) {
        if (threadIdx.x < off) sm[threadIdx.x] += sm[threadIdx.x + off];
        __syncthreads();
    }
    if (threadIdx.x == 0) partial[blockIdx.x] = sm[0];
}

__global__ void scan_chunkbase_kernel(int* __restrict__ partial,
                                      int* __restrict__ base,
                                      int nchunks, int n)
{
    if (threadIdx.x == 0 && blockIdx.x == 0) {
        int run = 0;
        for (int k = 0; k < nchunks; ++k) {
            int t = partial[k];
            partial[k] = run;
            run += t;
        }
        base[n] = run;
    }
}

__global__ __launch_bounds__(1024) void scan_apply_kernel(
    const int* __restrict__ count, const int* __restrict__ chunk_base,
    int* __restrict__ base, int* __restrict__ cursor, int n)
{
    __shared__ int sm[SCAN_CHUNK];
    const int t = threadIdx.x;
    const int i = blockIdx.x * SCAN_CHUNK + t;
    int v = (i < n) ? count[i] : 0;
    sm[t] = v;
    __syncthreads();
    for (int off = 1; off < SCAN_CHUNK; off <<= 1) {
        int tmp = (t >= off) ? sm[t - off] : 0;
        __syncthreads();
        sm[t] += tmp;
        __syncthreads();
    }
    if (i < n) {
        int excl = sm[t] - v + chunk_base[blockIdx.x];
        base[i] = excl;
        cursor[i] = excl;
    }
}

// also records the owner atom of each perm slot (sequential-read later)
__global__ __launch_bounds__(256) void fill_perm_kernel(
    const int* __restrict__ idx, int* __restrict__ cursor,
    int* __restrict__ perm, int* __restrict__ own, int E)
{
    int e = blockIdx.x * blockDim.x + threadIdx.x;
    if (e < E) {
        int a = idx[e];
        int pos = atomicAdd(&cursor[a], 1);
        perm[pos] = e;
        own[pos] = a;
    }
}

// ---------------------------------------------------------------------------
// Gather kernel: round-10 exact (best measured: 243 us gather, 329.7 total).
// One 128-thread block (thread = channel) per 128-edge slab; cooperative rbf
// staging to LDS ping-pong; x double-buffered in registers; segmented
// flush-on-owner-change; atomics only at slab boundaries.
// Plateau: 11 schedule variants converge at ~242-260 us ≈ 2.0 TB/s delivered
// on random 512B/128B granules — per-CU outstanding-request cap x loaded
// latency, a hardware concurrency wall.
// ---------------------------------------------------------------------------
__global__ __launch_bounds__(128, 2) void gather_kernel(
    const float* __restrict__ x,       // [E][C]
    const float* __restrict__ rbf,     // [E][RBFD]
    const float* __restrict__ env,     // [E]
    const int*   __restrict__ perm,    // [E]
    const int*   __restrict__ own,     // [E]
    const float* __restrict__ Wrbf,    // [C][RBFD]
    const float* __restrict__ brbf,    // [C]
    float* __restrict__ acc)           // [N][C] (pre-zeroed)
{
    __shared__ int   e_s[SLAB];
    __shared__ float env_s[SLAB];
    __shared__ int   own_s[SLAB];
    __shared__ float rbf_s[2][SS][RBFD];   // 2 x 2560 B, rows 16B-aligned

    const int tid = threadIdx.x;      // 0..127, = channel
    const int p0  = blockIdx.x * SLAB;

    {   // SLAB == blockDim.x: one staging pass, fully coalesced perm/own
        const int e = perm[p0 + tid];
        e_s[tid]   = e;
        env_s[tid] = env[e];
        own_s[tid] = own[p0 + tid];
    }

    float w[RBFD];
#pragma unroll
    for (int r = 0; r < RBFD; ++r) w[r] = Wrbf[tid * RBFD + r];
    const float bias = brbf[tid];

    __syncthreads();

    const int first_own = own_s[0];
    int   cur_own = first_own;
    float sum = 0.0f;

#define FLUSH()                                                                \
    do {                                                                       \
        if (cur_own == first_own)                                              \
            unsafeAtomicAdd(&acc[(size_t)cur_own * C + tid], sum);             \
        else acc[(size_t)cur_own * C + tid] = sum;                             \
    } while (0)

    float xr[2][SS];   // x double-buffer (fully unrolled -> registers)
    float st[5];       // rbf staging registers

    // ---- prologue: stage sub-slab 0 ----
#pragma unroll
    for (int p = 0; p < 5; ++p) {
        const int g = p * 128 + tid;            // 0..639
        st[p] = rbf[(size_t)e_s[g / RBFD] * RBFD + (g % RBFD)];
    }
#pragma unroll
    for (int i = 0; i < SS; ++i)
        xr[0][i] = x[(size_t)e_s[i] * C + tid];
    __builtin_amdgcn_sched_barrier(0);
#pragma unroll
    for (int p = 0; p < 5; ++p) {
        const int g = p * 128 + tid;
        rbf_s[0][g / RBFD][g % RBFD] = st[p];
    }
    __syncthreads();

#pragma unroll
    for (int ss = 0; ss < NSS; ++ss) {
        const int sbase = ss * SS;
        const int cur   = ss & 1;

        // ---- issue next sub-slab's loads (rbf -> regs, x -> regs) ----
        if (ss + 1 < NSS) {
#pragma unroll
            for (int p = 0; p < 5; ++p) {
                const int g = p * 128 + tid;
                st[p] = rbf[(size_t)e_s[sbase + SS + g / RBFD] * RBFD + (g % RBFD)];
            }
#pragma unroll
            for (int i = 0; i < SS; ++i)
                xr[cur ^ 1][i] = x[(size_t)e_s[sbase + SS + i] * C + tid];
        }
        __builtin_amdgcn_sched_barrier(0);

        // ---- compute current sub-slab (LDS broadcasts + registers only) ----
#pragma unroll
        for (int j = 0; j < SS; ++j) {
            const float4* q = reinterpret_cast<const float4*>(&rbf_s[cur][j][0]);
            const float4 a = q[0], b = q[1], c = q[2], d = q[3], e4 = q[4];
            float f = bias;
            f = fmaf(a.x,  w[0],  f); f = fmaf(a.y,  w[1],  f);
            f = fmaf(a.z,  w[2],  f); f = fmaf(a.w,  w[3],  f);
            f = fmaf(b.x,  w[4],  f); f = fmaf(b.y,  w[5],  f);
            f = fmaf(b.z,  w[6],  f); f = fmaf(b.w,  w[7],  f);
            f = fmaf(c.x,  w[8],  f); f = fmaf(c.y,  w[9],  f);
            f = fmaf(c.z,  w[10], f); f = fmaf(c.w,  w[11], f);
            f = fmaf(d.x,  w[12], f); f = fmaf(d.y,  w[13], f);
            f = fmaf(d.z,  w[14], f); f = fmaf(d.w,  w[15], f);
            f = fmaf(e4.x, w[16], f); f = fmaf(e4.y, w[17], f);
            f = fmaf(e4.z, w[18], f); f = fmaf(e4.w, w[19], f);

            const float v = f * env_s[sbase + j] * xr[cur][j];
            const int   o = own_s[sbase + j];
            if (o != cur_own) { FLUSH(); sum = 0.0f; cur_own = o; }
            sum += v;
        }

        // ---- write staged rbf to the other LDS buffer ----
        if (ss + 1 < NSS) {
#pragma unroll
            for (int p = 0; p < 5; ++p) {
                const int g = p * 128 + tid;
                rbf_s[cur ^ 1][g / RBFD][g % RBFD] = st[p];
            }
        }
        __syncthreads();
    }
    // final flush: cur_own may span into next slab -> atomic
    unsafeAtomicAdd(&acc[(size_t)cur_own * C + tid], sum);
#undef FLUSH
}

// ---------------------------------------------------------------------------
// Fused MLP head (round-10 exact: 128 atoms per block).
// ---------------------------------------------------------------------------
__device__ __forceinline__ float silu_f(float v) {
    return v * (1.0f / (1.0f + __expf(-v)));
}

__global__ __launch_bounds__(256) void mlp_head_kernel(
    const float* __restrict__ acc,   // [N][C]
    const float* __restrict__ W1T,   // [C][C]  (k-major)
    const float* __restrict__ b1,    // [C]
    const float* __restrict__ W2T,   // [C][C]
    const float* __restrict__ b2,    // [C]
    const float* __restrict__ W3,    // [1][C]
    const float* __restrict__ b3,    // [1]
    float* __restrict__ out,         // [N]
    int natoms)
{
    __shared__ float As[C][C + 1];

    const int tid = threadIdx.x;
    const int a0  = blockIdx.x * C;
    const int tc  = tid & 15;
    const int ta  = tid >> 4;
    const int abase = ta * 8;
    const int cbase = tc * 8;

    {
        const int sub = tid >> 7;
        const int k   = tid & 127;
        for (int pair = 0; pair < 64; ++pair) {
            const int al = pair * 2 + sub;
            const int a  = a0 + al;
            float v = (a < natoms) ? acc[(size_t)a * C + k] : 0.0f;
            As[k][al] = v;
        }
    }
    __syncthreads();

    float r[8][8];

    // layer 1
#pragma unroll
    for (int i = 0; i < 8; ++i)
#pragma unroll
        for (int j = 0; j < 8; ++j) r[i][j] = 0.0f;

#pragma unroll 2
    for (int k = 0; k < C; ++k) {
        float4 bq0 = *reinterpret_cast<const float4*>(W1T + k * C + cbase);
        float4 bq1 = *reinterpret_cast<const float4*>(W1T + k * C + cbase + 4);
        float bv[8] = {bq0.x, bq0.y, bq0.z, bq0.w, bq1.x, bq1.y, bq1.z, bq1.w};
        float av[8];
#pragma unroll
        for (int i = 0; i < 8; ++i) av[i] = As[k][abase + i];
#pragma unroll
        for (int i = 0; i < 8; ++i)
#pragma unroll
            for (int j = 0; j < 8; ++j) r[i][j] = fmaf(av[i], bv[j], r[i][j]);
    }

    __syncthreads();
    {
        float bb[8];
#pragma unroll
        for (int j = 0; j < 8; ++j) bb[j] = b1[cbase + j];
#pragma unroll
        for (int i = 0; i < 8; ++i)
#pragma unroll
            for (int j = 0; j < 8; ++j)
                As[cbase + j][abase + i] = silu_f(r[i][j] + bb[j]);
    }
    __syncthreads();

    // layer 2
#pragma unroll
    for (int i = 0; i < 8; ++i)
#pragma unroll
        for (int j = 0; j < 8; ++j) r[i][j] = 0.0f;

#pragma unroll 2
    for (int k = 0; k < C; ++k) {
        float4 bq0 = *reinterpret_cast<const float4*>(W2T + k * C + cbase);
        float4 bq1 = *reinterpret_cast<const float4*>(W2T + k * C + cbase + 4);
        float bv[8] = {bq0.x, bq0.y, bq0.z, bq0.w, bq1.x, bq1.y, bq1.z, bq1.w};
        float av[8];
#pragma unroll
        for (int i = 0; i < 8; ++i) av[i] = As[k][abase + i];
#pragma unroll
        for (int i = 0; i < 8; ++i)
#pragma unroll
            for (int j = 0; j < 8; ++j) r[i][j] = fmaf(av[i], bv[j], r[i][j]);
    }

    __syncthreads();

    // final: silu(.. + b2) . W3
    {
        float bb[8], w3v[8];
#pragma unroll
        for (int j = 0; j < 8; ++j) bb[j] = b2[cbase + j];
        float4 wq0 = *reinterpret_cast<const float4*>(W3 + cbase);
        float4 wq1 = *reinterpret_cast<const float4*>(W3 + cbase + 4);
        w3v[0]=wq0.x; w3v[1]=wq0.y; w3v[2]=wq0.z; w3v[3]=wq0.w;
        w3v[4]=wq1.x; w3v[5]=wq1.y; w3v[6]=wq1.z; w3v[7]=wq1.w;

#pragma unroll
        for (int i = 0; i < 8; ++i) {
            float p = 0.0f;
#pragma unroll
            for (int j = 0; j < 8; ++j)
                p = fmaf(silu_f(r[i][j] + bb[j]), w3v[j], p);
            As[abase + i][tc] = p;
        }
    }
    __syncthreads();

    if (tid < C) {
        const int a = a0 + tid;
        if (a < natoms) {
            float s = 0.0f;
#pragma unroll
            for (int t = 0; t < 16; ++t) s += As[tid][t];
            out[a] = s + b3[0];
        }
    }
}

// ---------------------------------------------------------------------------
extern "C" void kernel_launch(void* const* d_in, const int* in_sizes, int n_in,
                              void* d_out, int out_size, void* d_ws, size_t ws_size,
                              hipStream_t stream) {
    const float* x      = (const float*)d_in[0];
    const float* rbf    = (const float*)d_in[1];
    const float* env    = (const float*)d_in[2];
    const int*   idx    = (const int*)  d_in[3];
    const float* Wrbf   = (const float*)d_in[5];
    const float* brbf   = (const float*)d_in[6];
    const float* W1     = (const float*)d_in[7];
    const float* b1     = (const float*)d_in[8];
    const float* W2     = (const float*)d_in[9];
    const float* b2     = (const float*)d_in[10];
    const float* W3     = (const float*)d_in[11];
    const float* b3     = (const float*)d_in[12];
    float*       out    = (float*)d_out;

    const int E = in_sizes[0] / C;        // 800000
    const int N = NATOMS;                 // 50000
    const int nchunks = (N + SCAN_CHUNK - 1) / SCAN_CHUNK;   // 49

    // workspace layout
    float* acc     = (float*)d_ws;                    // N*C
    float* W1T     = acc + (size_t)N * C;             // C*C
    float* W2T     = W1T + C * C;                     // C*C
    int*   count   = (int*)(W2T + C * C);             // N
    int*   base    = count + N;                       // N+1
    int*   cursor  = base + (N + 1);                  // N
    int*   partial = cursor + N;                      // 64
    int*   perm    = partial + 64;                    // E
    int*   own     = perm + E;                        // E

    // setup: transpose weights + zero counters + zero acc
    setup_kernel<<<2048, 256, 0, stream>>>(W1, W2, W1T, W2T, count,
                                           (float4*)acc, N, (N * C) / 4);

    histogram_kernel<<<(E + 255) / 256, 256, 0, stream>>>(idx, count, E);
    scan_partials_kernel<<<nchunks, 256, 0, stream>>>(count, partial, N);
    scan_chunkbase_kernel<<<1, 64, 0, stream>>>(partial, base, nchunks, N);
    scan_apply_kernel<<<nchunks, SCAN_CHUNK, 0, stream>>>(count, partial, base, cursor, N);
    fill_perm_kernel<<<(E + 255) / 256, 256, 0, stream>>>(idx, cursor, perm, own, E);

    // gather: one 128-thread block per 128-edge slab
    gather_kernel<<<E / SLAB, 128, 0, stream>>>(x, rbf, env, perm, own,
                                                Wrbf, brbf, acc);

    const int tiles = (N + C - 1) / C;
    mlp_head_kernel<<<tiles, 256, 0, stream>>>(acc, W1T, b1, W2T, b2, W3, b3, out, N);
}